// Round 2
// baseline (648.710 us; speedup 1.0000x reference)
//
#include <hip/hip_runtime.h>
#include <math.h>

#define D 256
#define NCODE 1024
#define V_TOTAL 65536
#define EPSF 1e-12f
#define ROWS 32            // x rows staged per block
#define LSTR 260           // padded LDS row stride (floats)

// ---------------- ws layout (in floats) ----------------
// cb_n   : 0         .. 262144   (1024 x 256, normalized codebook, row-major)
// cb_t   : 262144    .. 524288   (256 x 1024, normalized codebook, transposed [k][n])
// idx_ws : 524288    .. 589824   (65536 int32 winning indices)
// counts : 589824    .. 590848   (1024 u32 histogram)
// loss   : 590848               (1 f32 accumulator)

// ---------------- out layout (floats) ----------------
// 0                     : loss
// 1        .. +16777216 : quantized_st
// 16777217              : perplexity
// 16777218 .. +262144   : codebook_weight passthrough
// 17039362 .. +65536    : code_indices (as float values)

__global__ __launch_bounds__(256) void normalize_cb(const float* __restrict__ w,
                                                    float* __restrict__ cb_n,
                                                    float* __restrict__ cb_t) {
    const int wave = threadIdx.x >> 6;
    const int lane = threadIdx.x & 63;
    const int row  = blockIdx.x * 4 + wave;      // 256 blocks * 4 waves = 1024 rows
    float4 wv = *(const float4*)(w + (size_t)row * D + lane * 4);
    float s = wv.x * wv.x + wv.y * wv.y + wv.z * wv.z + wv.w * wv.w;
    #pragma unroll
    for (int off = 32; off; off >>= 1) s += __shfl_xor(s, off);
    const float scale = 1.0f / fmaxf(sqrtf(s), EPSF);
    float4 o;
    o.x = wv.x * scale; o.y = wv.y * scale; o.z = wv.z * scale; o.w = wv.w * scale;
    *(float4*)(cb_n + (size_t)row * D + lane * 4) = o;
    const int k = lane * 4;
    cb_t[(size_t)(k + 0) * NCODE + row] = o.x;
    cb_t[(size_t)(k + 1) * NCODE + row] = o.y;
    cb_t[(size_t)(k + 2) * NCODE + row] = o.z;
    cb_t[(size_t)(k + 3) * NCODE + row] = o.w;
}

// Main kernel: block handles 32 vectors; streams 1024 codes in 4 chunks of 256.
// 256 threads = 8 tm-groups (4 rows each) x 32 tn-groups (8 cols each).
// LDS = 32*260*4 = 33.3 KB -> 4 blocks/CU -> 16 waves/CU (vs 8 before).
__global__ __launch_bounds__(256, 4) void vq_main(const float* __restrict__ x,
                                                  const float* __restrict__ cb_t,
                                                  int* __restrict__ idx_ws,
                                                  unsigned int* __restrict__ counts,
                                                  float* __restrict__ loss_acc,
                                                  float* __restrict__ out_idx_f) {
    __shared__ float xl[ROWS * LSTR];
    __shared__ float nrm_s[ROWS];
    const int tid = threadIdx.x;
    const int v0  = blockIdx.x * ROWS;

    // ---- stage x tile (coalesced float4 reads, b128 LDS writes) ----
    const float4* xg = (const float4*)(x + (size_t)v0 * D);
    #pragma unroll
    for (int i = 0; i < 8; ++i) {
        const int f  = tid + i * 256;       // float4 index in tile, 0..2047
        const int m  = f >> 6;              // 64 float4 per row
        const int kk = (f & 63) << 2;
        float4 val = xg[f];
        *(float4*)&xl[m * LSTR + kk] = val;
    }
    __syncthreads();

    // ---- per-row norms from LDS (8 threads per row) ----
    {
        const int row = tid >> 3, part = tid & 7;
        float ss = 0.f;
        #pragma unroll
        for (int q = 0; q < 8; ++q) {
            float4 xv = *(const float4*)&xl[row * LSTR + part * 32 + q * 4];
            ss += xv.x * xv.x + xv.y * xv.y + xv.z * xv.z + xv.w * xv.w;
        }
        ss += __shfl_xor(ss, 1);
        ss += __shfl_xor(ss, 2);
        ss += __shfl_xor(ss, 4);
        if (part == 0) nrm_s[row] = fmaxf(sqrtf(ss), EPSF);
    }
    __syncthreads();

    const int tn = tid & 31, tm = tid >> 5;     // 8 tm groups x 32 tn groups
    float best[4]; int bidx[4];
    #pragma unroll
    for (int i = 0; i < 4; ++i) { best[i] = -3.4e38f; bidx[i] = 0; }

    const float* bp = cb_t + tn * 8;

    #pragma unroll 1
    for (int c = 0; c < 4; ++c) {               // 4 n-chunks of 256 codes
        const int n0 = c * 256 + tn * 8;
        const float* bc = bp + c * 256;
        float acc[4][8];
        #pragma unroll
        for (int i = 0; i < 4; ++i)
            #pragma unroll
            for (int j = 0; j < 8; ++j) acc[i][j] = 0.f;

        #pragma unroll 2
        for (int k4 = 0; k4 < 64; ++k4) {
            float4 xa[4];
            #pragma unroll
            for (int i = 0; i < 4; ++i)
                xa[i] = *(const float4*)&xl[(tm * 4 + i) * LSTR + k4 * 4];
            #pragma unroll
            for (int kk = 0; kk < 4; ++kk) {
                const float* bk = bc + (size_t)(k4 * 4 + kk) * NCODE;
                float4 b0 = *(const float4*)bk;
                float4 b1 = *(const float4*)(bk + 4);
                #pragma unroll
                for (int i = 0; i < 4; ++i) {
                    const float xv = ((const float*)&xa[i])[kk];
                    acc[i][0] = fmaf(xv, b0.x, acc[i][0]);
                    acc[i][1] = fmaf(xv, b0.y, acc[i][1]);
                    acc[i][2] = fmaf(xv, b0.z, acc[i][2]);
                    acc[i][3] = fmaf(xv, b0.w, acc[i][3]);
                    acc[i][4] = fmaf(xv, b1.x, acc[i][4]);
                    acc[i][5] = fmaf(xv, b1.y, acc[i][5]);
                    acc[i][6] = fmaf(xv, b1.z, acc[i][6]);
                    acc[i][7] = fmaf(xv, b1.w, acc[i][7]);
                }
            }
        }
        // running argmax (ascending n per thread; strict > keeps lowest index on ties)
        #pragma unroll
        for (int i = 0; i < 4; ++i)
            #pragma unroll
            for (int j = 0; j < 8; ++j) {
                if (acc[i][j] > best[i]) { best[i] = acc[i][j]; bidx[i] = n0 + j; }
            }
    }

    // ---- argmax reduce across the 32 tn lanes (low 5 bits of lane id) ----
    #pragma unroll
    for (int off = 16; off; off >>= 1) {
        #pragma unroll
        for (int i = 0; i < 4; ++i) {
            float ov = __shfl_xor(best[i], off);
            int   oi = __shfl_xor(bidx[i], off);
            if (ov > best[i] || (ov == best[i] && oi < bidx[i])) { best[i] = ov; bidx[i] = oi; }
        }
    }

    // ---- epilogue ----
    float lpart = 0.f;
    if (tn == 0) {
        #pragma unroll
        for (int i = 0; i < 4; ++i) {
            const int row = tm * 4 + i;
            const int v   = v0 + row;
            const float sim = best[i] / nrm_s[row];
            lpart += 2.f - 2.f * sim;
            idx_ws[v] = bidx[i];
            out_idx_f[v] = (float)bidx[i];
            atomicAdd(&counts[bidx[i]], 1u);
        }
    }
    #pragma unroll
    for (int off = 32; off; off >>= 1) lpart += __shfl_xor(lpart, off);
    if ((tid & 63) == 0) atomicAdd(loss_acc, lpart);
}

__global__ __launch_bounds__(256) void gather_q(const int* __restrict__ idx_ws,
                                                const float* __restrict__ cb_n,
                                                float* __restrict__ outq) {
    const int wave = threadIdx.x >> 6;
    const int lane = threadIdx.x & 63;
    const int v = blockIdx.x * 4 + wave;
    const int idx = idx_ws[v];
    float4 val = *(const float4*)(cb_n + (size_t)idx * D + lane * 4);
    *(float4*)(outq + (size_t)v * D + lane * 4) = val;
}

__global__ __launch_bounds__(1024) void finalize(const unsigned int* __restrict__ counts,
                                                 const float* __restrict__ loss_acc,
                                                 float* __restrict__ out_loss,
                                                 float* __restrict__ out_perp) {
    __shared__ float red[16];
    const int t = threadIdx.x;
    const float p = (float)counts[t] / 65536.0f;
    float term = p * logf(p + 1e-10f);
    #pragma unroll
    for (int off = 32; off; off >>= 1) term += __shfl_xor(term, off);
    if ((t & 63) == 0) red[t >> 6] = term;
    __syncthreads();
    if (t < 16) {
        float s = red[t];
        #pragma unroll
        for (int off = 8; off; off >>= 1) s += __shfl_xor(s, off);
        if (t == 0) {
            *out_perp = expf(-s);
            *out_loss = 1.25f * (*loss_acc) / 16777216.0f;
        }
    }
}

extern "C" void kernel_launch(void* const* d_in, const int* in_sizes, int n_in,
                              void* d_out, int out_size, void* d_ws, size_t ws_size,
                              hipStream_t stream) {
    const float* x  = (const float*)d_in[0];
    const float* cw = (const float*)d_in[1];
    float* out = (float*)d_out;
    float* ws  = (float*)d_ws;

    float* cb_n          = ws;
    float* cb_t          = ws + 262144;
    int* idx_ws          = (int*)(ws + 524288);
    unsigned int* counts = (unsigned int*)(ws + 589824);
    float* loss_acc      = ws + 590848;

    // zero histogram + loss accumulator (contiguous region)
    hipMemsetAsync(counts, 0, (1024 + 1) * sizeof(float), stream);

    normalize_cb<<<256, 256, 0, stream>>>(cw, cb_n, cb_t);
    vq_main<<<2048, 256, 0, stream>>>(x, cb_t, idx_ws, counts, loss_acc,
                                      out + 17039362);
    gather_q<<<16384, 256, 0, stream>>>(idx_ws, cb_n, out + 1);
    finalize<<<1, 1024, 0, stream>>>(counts, loss_acc, out, out + 16777217);
    hipMemcpyAsync(out + 16777218, cw, (size_t)NCODE * D * sizeof(float),
                   hipMemcpyDeviceToDevice, stream);
}

// Round 3
// 587.691 us; speedup vs baseline: 1.1038x; 1.1038x over previous
//
#include <hip/hip_runtime.h>
#include <math.h>

#define D 256
#define NCODE 1024
#define EPSF 1e-12f
#define ROWS 32            // x rows staged per block
#define LSTR 260           // padded LDS row stride (floats)
#define SLABK 8            // k-rows per B slab
#define NSLAB 128          // 4 n-chunks x 32 k-slabs

// global -> LDS direct (16B per lane; LDS dest = wave-uniform base + lane*16)
#define GLOAD_LDS16(gp, lp) \
  __builtin_amdgcn_global_load_lds( \
      (const __attribute__((address_space(1))) unsigned int*)(const void*)(gp), \
      (__attribute__((address_space(3))) unsigned int*)(void*)(lp), 16, 0, 0)

// ---------------- ws layout (in floats) ----------------
// cb_n   : 0         .. 262144   (1024 x 256, normalized codebook, row-major)
// cb_t   : 262144    .. 524288   (256 x 1024, normalized codebook, transposed [k][n])
// idx_ws : 524288    .. 589824   (65536 int32 winning indices)
// counts : 589824    .. 590848   (1024 u32 histogram)
// loss   : 590848               (1 f32 accumulator)

// ---------------- out layout (floats) ----------------
// 0                     : loss
// 1        .. +16777216 : quantized_st
// 16777217              : perplexity
// 16777218 .. +262144   : codebook_weight passthrough
// 17039362 .. +65536    : code_indices (as float values)

__global__ __launch_bounds__(256) void normalize_cb(const float* __restrict__ w,
                                                    float* __restrict__ cb_n,
                                                    float* __restrict__ cb_t) {
    const int wave = threadIdx.x >> 6;
    const int lane = threadIdx.x & 63;
    const int row  = blockIdx.x * 4 + wave;      // 256 blocks * 4 waves = 1024 rows
    float4 wv = *(const float4*)(w + (size_t)row * D + lane * 4);
    float s = wv.x * wv.x + wv.y * wv.y + wv.z * wv.z + wv.w * wv.w;
    #pragma unroll
    for (int off = 32; off; off >>= 1) s += __shfl_xor(s, off);
    const float scale = 1.0f / fmaxf(sqrtf(s), EPSF);
    float4 o;
    o.x = wv.x * scale; o.y = wv.y * scale; o.z = wv.z * scale; o.w = wv.w * scale;
    *(float4*)(cb_n + (size_t)row * D + lane * 4) = o;
    const int k = lane * 4;
    cb_t[(size_t)(k + 0) * NCODE + row] = o.x;
    cb_t[(size_t)(k + 1) * NCODE + row] = o.y;
    cb_t[(size_t)(k + 2) * NCODE + row] = o.z;
    cb_t[(size_t)(k + 3) * NCODE + row] = o.w;
}

// Main kernel: block handles 32 vectors; 4 n-chunks of 256 codes, K streamed in
// 8-k slabs staged to LDS with global_load_lds (2-phase: issue next, compute cur).
// 256 threads = 8 tm-groups (4 rows each) x 32 tn-groups (8 cols each).
// LDS = 33.3 KB (x) + 16 KB (B dbuf) -> 3 blocks/CU.
__global__ __launch_bounds__(256, 3) void vq_main(const float* __restrict__ x,
                                                  const float* __restrict__ cb_t,
                                                  int* __restrict__ idx_ws,
                                                  unsigned int* __restrict__ counts,
                                                  float* __restrict__ loss_acc,
                                                  float* __restrict__ out_idx_f) {
    __shared__ float xl[ROWS * LSTR];
    __shared__ float bl[2][SLABK * 256];
    __shared__ float nrm_s[ROWS];
    const int tid  = threadIdx.x;
    const int wave = tid >> 6;
    const int lane = tid & 63;
    const int v0   = blockIdx.x * ROWS;

    // ---- stage x tile (coalesced float4 reads, b128 LDS writes) ----
    const float4* xg = (const float4*)(x + (size_t)v0 * D);
    #pragma unroll
    for (int i = 0; i < 8; ++i) {
        const int f  = tid + i * 256;       // float4 index in tile, 0..2047
        const int m  = f >> 6;              // 64 float4 per row
        const int kk = (f & 63) << 2;
        float4 val = xg[f];
        *(float4*)&xl[m * LSTR + kk] = val;
    }
    __syncthreads();

    // ---- issue slab 0 staging early (overlaps with norm compute) ----
    {
        const float* g = cb_t + (size_t)(wave * 2) * NCODE + lane * 4;
        GLOAD_LDS16(g,         &bl[0][(wave * 2 + 0) * 256]);
        GLOAD_LDS16(g + NCODE, &bl[0][(wave * 2 + 1) * 256]);
    }

    // ---- per-row norms from LDS (8 threads per row) ----
    {
        const int row = tid >> 3, part = tid & 7;
        float ss = 0.f;
        #pragma unroll
        for (int q = 0; q < 8; ++q) {
            float4 xv = *(const float4*)&xl[row * LSTR + part * 32 + q * 4];
            ss += xv.x * xv.x + xv.y * xv.y + xv.z * xv.z + xv.w * xv.w;
        }
        ss += __shfl_xor(ss, 1);
        ss += __shfl_xor(ss, 2);
        ss += __shfl_xor(ss, 4);
        if (part == 0) nrm_s[row] = fmaxf(sqrtf(ss), EPSF);
    }
    __syncthreads();   // drains vmcnt(0): slab 0 resident

    const int tn = tid & 31, tm = tid >> 5;     // 8 tm groups x 32 tn groups
    float best[4]; int bidx[4];
    #pragma unroll
    for (int i = 0; i < 4; ++i) { best[i] = -3.4e38f; bidx[i] = 0; }

    float acc[4][8];
    #pragma unroll
    for (int i = 0; i < 4; ++i)
        #pragma unroll
        for (int j = 0; j < 8; ++j) acc[i][j] = 0.f;

    // per-thread hoisted bases
    const float* xrow0 = &xl[(tm * 4 + 0) * LSTR];
    const float* xrow1 = &xl[(tm * 4 + 1) * LSTR];
    const float* xrow2 = &xl[(tm * 4 + 2) * LSTR];
    const float* xrow3 = &xl[(tm * 4 + 3) * LSTR];

    #pragma unroll 1
    for (int s = 0; s < NSLAB; ++s) {
        if (s) __syncthreads();         // slab s staged; buf (s+1)&1 free

        // issue next slab's staging before computing current (T3 2-phase)
        if (s + 1 < NSLAB) {
            const int c1  = (s + 1) >> 5;
            const int k01 = ((s + 1) & 31) * SLABK;
            float* dst = bl[(s + 1) & 1];
            const float* g = cb_t + (size_t)(k01 + wave * 2) * NCODE + c1 * 256 + lane * 4;
            GLOAD_LDS16(g,         dst + (wave * 2 + 0) * 256);
            GLOAD_LDS16(g + NCODE, dst + (wave * 2 + 1) * 256);
        }

        // compute 8 k's of current slab, all operands from LDS
        const float* btn = &bl[s & 1][tn * 8];
        const int kx0 = (s & 31) * SLABK;
        #pragma unroll
        for (int k4 = 0; k4 < 2; ++k4) {
            float4 xa0 = *(const float4*)(xrow0 + kx0 + k4 * 4);
            float4 xa1 = *(const float4*)(xrow1 + kx0 + k4 * 4);
            float4 xa2 = *(const float4*)(xrow2 + kx0 + k4 * 4);
            float4 xa3 = *(const float4*)(xrow3 + kx0 + k4 * 4);
            #pragma unroll
            for (int kk = 0; kk < 4; ++kk) {
                const float* bk = btn + (k4 * 4 + kk) * 256;   // compile-time imm offsets
                float4 b0 = *(const float4*)bk;
                float4 b1 = *(const float4*)(bk + 4);
                const float xv0 = ((const float*)&xa0)[kk];
                const float xv1 = ((const float*)&xa1)[kk];
                const float xv2 = ((const float*)&xa2)[kk];
                const float xv3 = ((const float*)&xa3)[kk];
                float xv[4] = {xv0, xv1, xv2, xv3};
                #pragma unroll
                for (int i = 0; i < 4; ++i) {
                    acc[i][0] = fmaf(xv[i], b0.x, acc[i][0]);
                    acc[i][1] = fmaf(xv[i], b0.y, acc[i][1]);
                    acc[i][2] = fmaf(xv[i], b0.z, acc[i][2]);
                    acc[i][3] = fmaf(xv[i], b0.w, acc[i][3]);
                    acc[i][4] = fmaf(xv[i], b1.x, acc[i][4]);
                    acc[i][5] = fmaf(xv[i], b1.y, acc[i][5]);
                    acc[i][6] = fmaf(xv[i], b1.z, acc[i][6]);
                    acc[i][7] = fmaf(xv[i], b1.w, acc[i][7]);
                }
            }
        }

        // end of an n-chunk: fold acc into running argmax, reset acc
        if ((s & 31) == 31) {
            const int n0 = (s >> 5) * 256 + tn * 8;
            #pragma unroll
            for (int i = 0; i < 4; ++i)
                #pragma unroll
                for (int j = 0; j < 8; ++j) {
                    if (acc[i][j] > best[i]) { best[i] = acc[i][j]; bidx[i] = n0 + j; }
                    acc[i][j] = 0.f;
                }
        }
    }

    // ---- argmax reduce across the 32 tn lanes (low 5 bits of lane id) ----
    #pragma unroll
    for (int off = 16; off; off >>= 1) {
        #pragma unroll
        for (int i = 0; i < 4; ++i) {
            float ov = __shfl_xor(best[i], off);
            int   oi = __shfl_xor(bidx[i], off);
            if (ov > best[i] || (ov == best[i] && oi < bidx[i])) { best[i] = ov; bidx[i] = oi; }
        }
    }

    // ---- epilogue ----
    float lpart = 0.f;
    if (tn == 0) {
        #pragma unroll
        for (int i = 0; i < 4; ++i) {
            const int row = tm * 4 + i;
            const int v   = v0 + row;
            const float sim = best[i] / nrm_s[row];
            lpart += 2.f - 2.f * sim;
            idx_ws[v] = bidx[i];
            out_idx_f[v] = (float)bidx[i];
            atomicAdd(&counts[bidx[i]], 1u);
        }
    }
    #pragma unroll
    for (int off = 32; off; off >>= 1) lpart += __shfl_xor(lpart, off);
    if ((tid & 63) == 0) atomicAdd(loss_acc, lpart);
}

__global__ __launch_bounds__(256) void gather_q(const int* __restrict__ idx_ws,
                                                const float* __restrict__ cb_n,
                                                float* __restrict__ outq) {
    const int wave = threadIdx.x >> 6;
    const int lane = threadIdx.x & 63;
    const int v = blockIdx.x * 4 + wave;
    const int idx = idx_ws[v];
    float4 val = *(const float4*)(cb_n + (size_t)idx * D + lane * 4);
    *(float4*)(outq + (size_t)v * D + lane * 4) = val;
}

__global__ __launch_bounds__(1024) void finalize(const unsigned int* __restrict__ counts,
                                                 const float* __restrict__ loss_acc,
                                                 float* __restrict__ out_loss,
                                                 float* __restrict__ out_perp) {
    __shared__ float red[16];
    const int t = threadIdx.x;
    const float p = (float)counts[t] / 65536.0f;
    float term = p * logf(p + 1e-10f);
    #pragma unroll
    for (int off = 32; off; off >>= 1) term += __shfl_xor(term, off);
    if ((t & 63) == 0) red[t >> 6] = term;
    __syncthreads();
    if (t < 16) {
        float s = red[t];
        #pragma unroll
        for (int off = 8; off; off >>= 1) s += __shfl_xor(s, off);
        if (t == 0) {
            *out_perp = expf(-s);
            *out_loss = 1.25f * (*loss_acc) / 16777216.0f;
        }
    }
}

extern "C" void kernel_launch(void* const* d_in, const int* in_sizes, int n_in,
                              void* d_out, int out_size, void* d_ws, size_t ws_size,
                              hipStream_t stream) {
    const float* x  = (const float*)d_in[0];
    const float* cw = (const float*)d_in[1];
    float* out = (float*)d_out;
    float* ws  = (float*)d_ws;

    float* cb_n          = ws;
    float* cb_t          = ws + 262144;
    int* idx_ws          = (int*)(ws + 524288);
    unsigned int* counts = (unsigned int*)(ws + 589824);
    float* loss_acc      = ws + 590848;

    // zero histogram + loss accumulator (contiguous region)
    hipMemsetAsync(counts, 0, (1024 + 1) * sizeof(float), stream);

    normalize_cb<<<256, 256, 0, stream>>>(cw, cb_n, cb_t);
    vq_main<<<2048, 256, 0, stream>>>(x, cb_t, idx_ws, counts, loss_acc,
                                      out + 17039362);
    gather_q<<<16384, 256, 0, stream>>>(idx_ws, cb_n, out + 1);
    finalize<<<1, 1024, 0, stream>>>(counts, loss_acc, out, out + 16777217);
    hipMemcpyAsync(out + 16777218, cw, (size_t)NCODE * D * sizeof(float),
                   hipMemcpyDeviceToDevice, stream);
}

// Round 4
// 582.969 us; speedup vs baseline: 1.1128x; 1.0081x over previous
//
#include <hip/hip_runtime.h>
#include <math.h>

#define D 256
#define NCODE 1024
#define EPSF 1e-12f
#define ROWS 32            // x rows staged per block
#define SLABK 4            // k-rows per B slab
#define NSLAB 256          // 4 n-chunks x 64 k-slabs

// global -> LDS direct (16B per lane; LDS dest = wave-uniform base + lane*16)
#define GLOAD_LDS16(gp, lp) \
  __builtin_amdgcn_global_load_lds( \
      (const __attribute__((address_space(1))) unsigned int*)(const void*)(gp), \
      (__attribute__((address_space(3))) unsigned int*)(void*)(lp), 16, 0, 0)

// ---------------- ws layout (in floats) ----------------
// cb_n   : 0         .. 262144   (1024 x 256, normalized codebook, row-major)
// cb_t   : 262144    .. 524288   (256 x 1024, normalized codebook, transposed [k][n])
// idx_ws : 524288    .. 589824   (65536 int32 winning indices)
// counts : 589824    .. 590848   (1024 u32 histogram)
// loss   : 590848               (1 f32 accumulator)

// ---------------- out layout (floats) ----------------
// 0                     : loss
// 1        .. +16777216 : quantized_st
// 16777217              : perplexity
// 16777218 .. +262144   : codebook_weight passthrough
// 17039362 .. +65536    : code_indices (as float values)

__global__ __launch_bounds__(256) void normalize_cb(const float* __restrict__ w,
                                                    float* __restrict__ cb_n,
                                                    float* __restrict__ cb_t) {
    const int wave = threadIdx.x >> 6;
    const int lane = threadIdx.x & 63;
    const int row  = blockIdx.x * 4 + wave;      // 256 blocks * 4 waves = 1024 rows
    float4 wv = *(const float4*)(w + (size_t)row * D + lane * 4);
    float s = wv.x * wv.x + wv.y * wv.y + wv.z * wv.z + wv.w * wv.w;
    #pragma unroll
    for (int off = 32; off; off >>= 1) s += __shfl_xor(s, off);
    const float scale = 1.0f / fmaxf(sqrtf(s), EPSF);
    float4 o;
    o.x = wv.x * scale; o.y = wv.y * scale; o.z = wv.z * scale; o.w = wv.w * scale;
    *(float4*)(cb_n + (size_t)row * D + lane * 4) = o;
    const int k = lane * 4;
    cb_t[(size_t)(k + 0) * NCODE + row] = o.x;
    cb_t[(size_t)(k + 1) * NCODE + row] = o.y;
    cb_t[(size_t)(k + 2) * NCODE + row] = o.z;
    cb_t[(size_t)(k + 3) * NCODE + row] = o.w;
}

// Main kernel: block handles 32 vectors; 4 n-chunks of 256 codes, K streamed in
// 4-k slabs staged to LDS with global_load_lds (2-phase: issue next, compute cur).
// 256 threads = 8 tm-groups (4 rows each) x 32 tn-groups (8 codes each).
// Per-thread codes per chunk: {tn*4..tn*4+3} and {128+tn*4..+3}  -> both b128
// reads are lane-consecutive-16B = bank-conflict-free.
// LDS = 32*256*4 (x) + 2*4*256*4 (B dbuf) = 40960 B exactly -> 4 blocks/CU.
__global__ __launch_bounds__(256, 4) void vq_main(const float* __restrict__ x,
                                                  const float* __restrict__ cb_t,
                                                  int* __restrict__ idx_ws,
                                                  unsigned int* __restrict__ counts,
                                                  float* __restrict__ loss_acc,
                                                  float* __restrict__ out_idx_f) {
    __shared__ float xl[ROWS * 256];
    __shared__ float bl[2][SLABK * 256];
    const int tid  = threadIdx.x;
    const int wave = tid >> 6;
    const int lane = tid & 63;
    const int v0   = blockIdx.x * ROWS;

    // ---- stage x tile (fully linear: thread f writes bytes f*16) ----
    const float4* xg = (const float4*)(x + (size_t)v0 * D);
    #pragma unroll
    for (int i = 0; i < 8; ++i) {
        const int f = tid + i * 256;        // float4 index in tile, 0..2047
        float4 val = xg[f];
        *(float4*)&xl[f * 4] = val;
    }
    __syncthreads();

    // ---- issue slab 0 staging early (overlaps with norm compute) ----
    {
        const float* g = cb_t + (size_t)wave * NCODE + lane * 4;
        GLOAD_LDS16(g, &bl[0][wave * 256]);
    }

    const int tn = tid & 31, tm = tid >> 5;     // 8 tm groups x 32 tn groups

    // ---- per-row norms in registers (tn-group shuffle reduce; conflict-free) ----
    float nrm[4];
    #pragma unroll
    for (int i = 0; i < 4; ++i) {
        const float* xr = &xl[(tm * 4 + i) * 256];
        float4 a = *(const float4*)(xr + tn * 4);
        float4 b = *(const float4*)(xr + 128 + tn * 4);
        float ss = a.x * a.x + a.y * a.y + a.z * a.z + a.w * a.w
                 + b.x * b.x + b.y * b.y + b.z * b.z + b.w * b.w;
        ss += __shfl_xor(ss, 16);
        ss += __shfl_xor(ss, 8);
        ss += __shfl_xor(ss, 4);
        ss += __shfl_xor(ss, 2);
        ss += __shfl_xor(ss, 1);
        nrm[i] = fmaxf(sqrtf(ss), EPSF);
    }
    __syncthreads();   // drains vmcnt(0): slab 0 resident

    float best[4]; int bidx[4];
    #pragma unroll
    for (int i = 0; i < 4; ++i) { best[i] = -3.4e38f; bidx[i] = 0; }

    float acc[4][8];
    #pragma unroll
    for (int i = 0; i < 4; ++i)
        #pragma unroll
        for (int j = 0; j < 8; ++j) acc[i][j] = 0.f;

    const float* xrow0 = &xl[(tm * 4 + 0) * 256];
    const float* xrow1 = &xl[(tm * 4 + 1) * 256];
    const float* xrow2 = &xl[(tm * 4 + 2) * 256];
    const float* xrow3 = &xl[(tm * 4 + 3) * 256];

    #pragma unroll 1
    for (int s = 0; s < NSLAB; ++s) {
        if (s) __syncthreads();         // slab s staged; buf (s+1)&1 free

        // issue next slab's staging before computing current (T3 2-phase)
        if (s + 1 < NSLAB) {
            const int sn = s + 1;
            const int c1 = sn >> 6;
            const int k1 = ((sn & 63) << 2) + wave;   // k-row this wave stages
            const float* g = cb_t + (size_t)k1 * NCODE + c1 * 256 + lane * 4;
            GLOAD_LDS16(g, &bl[sn & 1][wave * 256]);
        }

        // compute 4 k's of current slab, all operands from LDS
        const float* bs = &bl[s & 1][tn * 4];
        const int kx0 = (s & 63) << 2;
        float4 xa0 = *(const float4*)(xrow0 + kx0);
        float4 xa1 = *(const float4*)(xrow1 + kx0);
        float4 xa2 = *(const float4*)(xrow2 + kx0);
        float4 xa3 = *(const float4*)(xrow3 + kx0);
        #pragma unroll
        for (int kk = 0; kk < 4; ++kk) {
            float4 b0 = *(const float4*)(bs + kk * 256);          // codes tn*4..+3
            float4 b1 = *(const float4*)(bs + kk * 256 + 128);    // codes 128+tn*4..+3
            const float xv0 = ((const float*)&xa0)[kk];
            const float xv1 = ((const float*)&xa1)[kk];
            const float xv2 = ((const float*)&xa2)[kk];
            const float xv3 = ((const float*)&xa3)[kk];
            float xv[4] = {xv0, xv1, xv2, xv3};
            #pragma unroll
            for (int i = 0; i < 4; ++i) {
                acc[i][0] = fmaf(xv[i], b0.x, acc[i][0]);
                acc[i][1] = fmaf(xv[i], b0.y, acc[i][1]);
                acc[i][2] = fmaf(xv[i], b0.z, acc[i][2]);
                acc[i][3] = fmaf(xv[i], b0.w, acc[i][3]);
                acc[i][4] = fmaf(xv[i], b1.x, acc[i][4]);
                acc[i][5] = fmaf(xv[i], b1.y, acc[i][5]);
                acc[i][6] = fmaf(xv[i], b1.z, acc[i][6]);
                acc[i][7] = fmaf(xv[i], b1.w, acc[i][7]);
            }
        }

        // end of an n-chunk: fold acc into running argmax, reset acc
        if ((s & 63) == 63) {
            const int n0 = (s >> 6) * 256 + tn * 4;
            #pragma unroll
            for (int i = 0; i < 4; ++i) {
                #pragma unroll
                for (int j = 0; j < 4; ++j) {
                    if (acc[i][j] > best[i]) { best[i] = acc[i][j]; bidx[i] = n0 + j; }
                    acc[i][j] = 0.f;
                }
                #pragma unroll
                for (int j = 4; j < 8; ++j) {
                    if (acc[i][j] > best[i]) { best[i] = acc[i][j]; bidx[i] = n0 + 128 + (j - 4); }
                    acc[i][j] = 0.f;
                }
            }
        }
    }

    // ---- argmax reduce across the 32 tn lanes (low 5 bits of lane id) ----
    #pragma unroll
    for (int off = 16; off; off >>= 1) {
        #pragma unroll
        for (int i = 0; i < 4; ++i) {
            float ov = __shfl_xor(best[i], off);
            int   oi = __shfl_xor(bidx[i], off);
            if (ov > best[i] || (ov == best[i] && oi < bidx[i])) { best[i] = ov; bidx[i] = oi; }
        }
    }

    // ---- epilogue ----
    float lpart = 0.f;
    if (tn == 0) {
        #pragma unroll
        for (int i = 0; i < 4; ++i) {
            const int row = tm * 4 + i;
            const int v   = v0 + row;
            const float sim = best[i] / nrm[i];
            lpart += 2.f - 2.f * sim;
            idx_ws[v] = bidx[i];
            out_idx_f[v] = (float)bidx[i];
            atomicAdd(&counts[bidx[i]], 1u);
        }
    }
    #pragma unroll
    for (int off = 32; off; off >>= 1) lpart += __shfl_xor(lpart, off);
    if ((tid & 63) == 0) atomicAdd(loss_acc, lpart);
}

__global__ __launch_bounds__(256) void gather_q(const int* __restrict__ idx_ws,
                                                const float* __restrict__ cb_n,
                                                float* __restrict__ outq) {
    const int wave = threadIdx.x >> 6;
    const int lane = threadIdx.x & 63;
    const int v = blockIdx.x * 4 + wave;
    const int idx = idx_ws[v];
    float4 val = *(const float4*)(cb_n + (size_t)idx * D + lane * 4);
    *(float4*)(outq + (size_t)v * D + lane * 4) = val;
}

__global__ __launch_bounds__(1024) void finalize(const unsigned int* __restrict__ counts,
                                                 const float* __restrict__ loss_acc,
                                                 float* __restrict__ out_loss,
                                                 float* __restrict__ out_perp) {
    __shared__ float red[16];
    const int t = threadIdx.x;
    const float p = (float)counts[t] / 65536.0f;
    float term = p * logf(p + 1e-10f);
    #pragma unroll
    for (int off = 32; off; off >>= 1) term += __shfl_xor(term, off);
    if ((t & 63) == 0) red[t >> 6] = term;
    __syncthreads();
    if (t < 16) {
        float s = red[t];
        #pragma unroll
        for (int off = 8; off; off >>= 1) s += __shfl_xor(s, off);
        if (t == 0) {
            *out_perp = expf(-s);
            *out_loss = 1.25f * (*loss_acc) / 16777216.0f;
        }
    }
}

extern "C" void kernel_launch(void* const* d_in, const int* in_sizes, int n_in,
                              void* d_out, int out_size, void* d_ws, size_t ws_size,
                              hipStream_t stream) {
    const float* x  = (const float*)d_in[0];
    const float* cw = (const float*)d_in[1];
    float* out = (float*)d_out;
    float* ws  = (float*)d_ws;

    float* cb_n          = ws;
    float* cb_t          = ws + 262144;
    int* idx_ws          = (int*)(ws + 524288);
    unsigned int* counts = (unsigned int*)(ws + 589824);
    float* loss_acc      = ws + 590848;

    // zero histogram + loss accumulator (contiguous region)
    hipMemsetAsync(counts, 0, (1024 + 1) * sizeof(float), stream);

    normalize_cb<<<256, 256, 0, stream>>>(cw, cb_n, cb_t);
    vq_main<<<2048, 256, 0, stream>>>(x, cb_t, idx_ws, counts, loss_acc,
                                      out + 17039362);
    gather_q<<<16384, 256, 0, stream>>>(idx_ws, cb_n, out + 1);
    finalize<<<1, 1024, 0, stream>>>(counts, loss_acc, out, out + 16777217);
    hipMemcpyAsync(out + 16777218, cw, (size_t)NCODE * D * sizeof(float),
                   hipMemcpyDeviceToDevice, stream);
}